// Round 1
// baseline (3695.973 us; speedup 1.0000x reference)
//
#include <hip/hip_runtime.h>
#include <hip/hip_bf16.h>
#include <math.h>

#define B_  4
#define S_  2048
#define D_  1024
#define H_  16
#define HD_ 64
#define SD_  (S_*D_)        // 2097152
#define SHD_ (S_*HD_)       // 131072

// ---------------------------------------------------------------------------
// GEMM: C[8192,1024] = A[8192,1024] @ W[1024,1024]^T + bias
// 128x128 block tile, BK=16, 256 threads, 8x8 micro-tile per thread.
// ---------------------------------------------------------------------------
__global__ __launch_bounds__(256) void gemm_bt_8192(
    const float* __restrict__ A, const float* __restrict__ W,
    const float* __restrict__ bias, float* __restrict__ C)
{
  __shared__ float As[16*128];   // As[kk][m]
  __shared__ float Bs[16*128];   // Bs[kk][n]
  const int tid = threadIdx.x;
  const int tx = tid & 15;       // n direction
  const int ty = tid >> 4;       // m direction
  const int n0 = blockIdx.x * 128;
  const int m0 = blockIdx.y * 128;

  float acc[8][8];
#pragma unroll
  for (int i = 0; i < 8; ++i)
#pragma unroll
    for (int j = 0; j < 8; ++j) acc[i][j] = 0.f;

  const float4* A4 = (const float4*)A;
  const float4* W4 = (const float4*)W;

  for (int kt = 0; kt < 64; ++kt) {
#pragma unroll
    for (int uu = 0; uu < 2; ++uu) {
      int u  = tid + uu * 256;        // 0..511
      int r  = u >> 2;                // 0..127 (tile row)
      int c4 = u & 3;                 // which float4 along K-slice
      float4 av = A4[(size_t)(m0 + r) * 256 + kt * 4 + c4];
      As[(4*c4+0)*128 + r] = av.x;
      As[(4*c4+1)*128 + r] = av.y;
      As[(4*c4+2)*128 + r] = av.z;
      As[(4*c4+3)*128 + r] = av.w;
      float4 wv = W4[(size_t)(n0 + r) * 256 + kt * 4 + c4];
      Bs[(4*c4+0)*128 + r] = wv.x;
      Bs[(4*c4+1)*128 + r] = wv.y;
      Bs[(4*c4+2)*128 + r] = wv.z;
      Bs[(4*c4+3)*128 + r] = wv.w;
    }
    __syncthreads();
#pragma unroll
    for (int kk = 0; kk < 16; ++kk) {
      float4 a0 = ((const float4*)As)[kk*32 + ty*2];
      float4 a1 = ((const float4*)As)[kk*32 + ty*2 + 1];
      float4 b0 = ((const float4*)Bs)[kk*32 + tx*2];
      float4 b1 = ((const float4*)Bs)[kk*32 + tx*2 + 1];
      float a[8]  = {a0.x,a0.y,a0.z,a0.w,a1.x,a1.y,a1.z,a1.w};
      float bb[8] = {b0.x,b0.y,b0.z,b0.w,b1.x,b1.y,b1.z,b1.w};
#pragma unroll
      for (int i = 0; i < 8; ++i)
#pragma unroll
        for (int j = 0; j < 8; ++j)
          acc[i][j] = fmaf(a[i], bb[j], acc[i][j]);
    }
    __syncthreads();
  }

  const float4 bv0 = *(const float4*)&bias[n0 + tx*8];
  const float4 bv1 = *(const float4*)&bias[n0 + tx*8 + 4];
#pragma unroll
  for (int i = 0; i < 8; ++i) {
    int row = m0 + ty*8 + i;
    float4 o0 = make_float4(acc[i][0]+bv0.x, acc[i][1]+bv0.y,
                            acc[i][2]+bv0.z, acc[i][3]+bv0.w);
    float4 o1 = make_float4(acc[i][4]+bv1.x, acc[i][5]+bv1.y,
                            acc[i][6]+bv1.z, acc[i][7]+bv1.w);
    ((float4*)C)[(size_t)row*256 + (n0>>2) + tx*2    ] = o0;
    ((float4*)C)[(size_t)row*256 + (n0>>2) + tx*2 + 1] = o1;
  }
}

// ---------------------------------------------------------------------------
// Flash-style causal attention over the "scrambled" per-(b,h) views.
// Per (b,h): Q,K,V are contiguous 2048x64 row-major at offset bh*131072.
// One WG = 256 threads = 4 waves handles 64 Q rows (16 rows/wave, 2 groups
// of 8). Online softmax; scale 1/8 applied after masking (matches ref).
// Output written IN PLACE over Qp (only this WG reads those Q rows).
// ---------------------------------------------------------------------------
__global__ __launch_bounds__(256) void attn_kernel(
    float* __restrict__ Qp, const float* __restrict__ Kp,
    const float* __restrict__ Vp, const int* __restrict__ pad)
{
  __shared__ float Qs[64*64];     // 16 KB, unpadded (broadcast reads)
  __shared__ float Ks[64*68];     // K tile, f4 row stride 17 (odd -> no conflicts)
  __shared__ float Vst[64*68];    // V transposed: Vst[d][j], stride 68
  __shared__ float Ps[32*68];     // per-wave 8 softmax rows, stride 68

  const int tid  = threadIdx.x;
  const int lane = tid & 63;
  const int w    = tid >> 6;
  const int it   = blockIdx.x;    // Q tile index, 0..31
  const int bh   = blockIdx.y;    // b*16 + h
  const int b    = bh >> 4;
  const size_t qb  = (size_t)bh * SHD_;
  const size_t qb4 = qb >> 2;

  { // load Q tile (contiguous 1024 float4)
    const float4* src = (const float4*)Qp + qb4 + (size_t)it * 1024;
    float4* dst = (float4*)Qs;
    for (int u = tid; u < 1024; u += 256) dst[u] = src[u];
  }

  float m[16], l[16], o[16];
#pragma unroll
  for (int i = 0; i < 16; ++i) { m[i] = -INFINITY; l[i] = 0.f; o[i] = 0.f; }

  for (int jt = 0; jt <= it; ++jt) {
    __syncthreads();   // previous iteration's readers done before overwrite
    {
      const float4* ksrc = (const float4*)Kp + qb4 + (size_t)jt * 1024;
      const float4* vsrc = (const float4*)Vp + qb4 + (size_t)jt * 1024;
      for (int u = tid; u < 1024; u += 256) {
        int j = u >> 4, d4 = u & 15;
        ((float4*)Ks)[j*17 + d4] = ksrc[u];
        float4 vv = vsrc[u];
        Vst[(4*d4+0)*68 + j] = vv.x;
        Vst[(4*d4+1)*68 + j] = vv.y;
        Vst[(4*d4+2)*68 + j] = vv.z;
        Vst[(4*d4+3)*68 + j] = vv.w;
      }
    }
    __syncthreads();

    const int gj = jt*64 + lane;
    const bool padok = (pad[b*S_ + gj] != 0);

    for (int g = 0; g < 2; ++g) {
      const int r0 = w*16 + g*8;   // row base within WG tile
      float s[8];
#pragma unroll
      for (int r = 0; r < 8; ++r) s[r] = 0.f;

      // S = Q K^T : lane = column j, 8 rows at a time
#pragma unroll
      for (int d4 = 0; d4 < 16; ++d4) {
        float4 kv = ((const float4*)Ks)[lane*17 + d4];
#pragma unroll
        for (int r = 0; r < 8; ++r) {
          float4 qv = ((const float4*)Qs)[(r0 + r)*16 + d4];  // broadcast
          s[r] += qv.x*kv.x + qv.y*kv.y + qv.z*kv.z + qv.w*kv.w;
        }
      }

      // online softmax per row (scale AFTER masking, as in reference)
#pragma unroll
      for (int r = 0; r < 8; ++r) {
        const int li = g*8 + r;
        const int gi = it*64 + w*16 + li;
        float lg = (gj <= gi && padok) ? s[r] * 0.125f : -INFINITY;
        float mx = lg;
#pragma unroll
        for (int off = 32; off >= 1; off >>= 1) mx = fmaxf(mx, __shfl_xor(mx, off, 64));
        float mnew  = fmaxf(m[li], mx);
        float alpha = __expf(m[li] - mnew);   // m=-inf first tile -> 0
        float p     = __expf(lg - mnew);      // lg=-inf (masked) -> 0
        float sm = p;
#pragma unroll
        for (int off = 32; off >= 1; off >>= 1) sm += __shfl_xor(sm, off, 64);
        l[li] = l[li]*alpha + sm;
        m[li] = mnew;
        o[li] *= alpha;
        Ps[(w*8 + r)*68 + lane] = p;
      }
      __syncthreads();   // Ps visible (also keeps waves lockstep)

      // O += P V : lane = d, vectorized via transposed V
#pragma unroll
      for (int j4 = 0; j4 < 16; ++j4) {
        float4 vv = ((const float4*)Vst)[lane*17 + j4];
#pragma unroll
        for (int r = 0; r < 8; ++r) {
          float4 pv = ((const float4*)Ps)[(w*8 + r)*17 + j4];  // broadcast
          o[g*8 + r] += pv.x*vv.x + pv.y*vv.y + pv.z*vv.z + pv.w*vv.w;
        }
      }
      __syncthreads();   // protect Ps reuse by next g
    }
  }

  // epilogue: normalize and write back over Qp (in place, own rows only)
#pragma unroll
  for (int li = 0; li < 16; ++li) {
    const size_t row = (size_t)it*64 + w*16 + li;
    Qp[qb + row*64 + lane] = o[li] / l[li];
  }
}

// ---------------------------------------------------------------------------
// Residual + LayerNorm: out = gamma * (y - mean)/(std + 1e-8) + beta,
// y = x + O, per row of 1024. One block per row, one float4 per thread.
// ---------------------------------------------------------------------------
__global__ __launch_bounds__(256) void ln_kernel(
    const float* __restrict__ x, const float* __restrict__ O,
    const float* __restrict__ gamma, const float* __restrict__ beta,
    float* __restrict__ out)
{
  __shared__ float red[8];
  const int row = blockIdx.x;
  const int tid = threadIdx.x;
  float4 xv = ((const float4*)x)[(size_t)row*256 + tid];
  float4 ov = ((const float4*)O)[(size_t)row*256 + tid];
  float4 y  = make_float4(xv.x+ov.x, xv.y+ov.y, xv.z+ov.z, xv.w+ov.w);
  float s1 = y.x + y.y + y.z + y.w;
  float s2 = y.x*y.x + y.y*y.y + y.z*y.z + y.w*y.w;
#pragma unroll
  for (int off = 32; off >= 1; off >>= 1) {
    s1 += __shfl_xor(s1, off, 64);
    s2 += __shfl_xor(s2, off, 64);
  }
  if ((tid & 63) == 0) { red[tid>>6] = s1; red[4 + (tid>>6)] = s2; }
  __syncthreads();
  s1 = red[0] + red[1] + red[2] + red[3];
  s2 = red[4] + red[5] + red[6] + red[7];
  const float mean = s1 * (1.0f/1024.0f);
  const float var  = fmaxf(s2 * (1.0f/1024.0f) - mean*mean, 0.f);
  const float rstd = 1.0f / (sqrtf(var) + 1e-8f);
  float4 gv = ((const float4*)gamma)[tid];
  float4 bv = ((const float4*)beta)[tid];
  float4 r;
  r.x = gv.x*(y.x-mean)*rstd + bv.x;
  r.y = gv.y*(y.y-mean)*rstd + bv.y;
  r.z = gv.z*(y.z-mean)*rstd + bv.z;
  r.w = gv.w*(y.w-mean)*rstd + bv.w;
  ((float4*)out)[(size_t)row*256 + tid] = r;
}

// ---------------------------------------------------------------------------
extern "C" void kernel_launch(void* const* d_in, const int* in_sizes, int n_in,
                              void* d_out, int out_size, void* d_ws, size_t ws_size,
                              hipStream_t stream)
{
  const float* q  = (const float*)d_in[0];
  const float* k  = (const float*)d_in[1];
  const float* v  = (const float*)d_in[2];
  // d_in[3] = attn_mask (causal tril) — applied analytically via j<=i
  const int*   pad = (const int*)d_in[4];
  const float* Wq = (const float*)d_in[5];
  const float* bq = (const float*)d_in[6];
  const float* Wk = (const float*)d_in[7];
  const float* bk = (const float*)d_in[8];
  const float* Wv = (const float*)d_in[9];
  const float* bv = (const float*)d_in[10];
  const float* Wo = (const float*)d_in[11];
  const float* bo = (const float*)d_in[12];
  const float* gamma = (const float*)d_in[13];
  const float* beta  = (const float*)d_in[14];
  float* out = (float*)d_out;

  float* Qp = (float*)d_ws;                      // 32 MB
  float* Kp = Qp + (size_t)B_*S_*D_;             // 32 MB
  float* Vp = Kp + (size_t)B_*S_*D_;             // 32 MB

  dim3 gg(8, 64), bb(256);
  gemm_bt_8192<<<gg, bb, 0, stream>>>(q, Wq, bq, Qp);
  gemm_bt_8192<<<gg, bb, 0, stream>>>(k, Wk, bk, Kp);
  gemm_bt_8192<<<gg, bb, 0, stream>>>(v, Wv, bv, Vp);
  attn_kernel<<<dim3(32, 64), 256, 0, stream>>>(Qp, Kp, Vp, pad);  // Qp <- attn out (in place)
  gemm_bt_8192<<<gg, bb, 0, stream>>>(Qp, Wo, bo, Kp);             // Kp <- O projection
  ln_kernel<<<dim3(B_*S_), 256, 0, stream>>>(q, Kp, gamma, beta, out);
}

// Round 2
// 1394.300 us; speedup vs baseline: 2.6508x; 2.6508x over previous
//
#include <hip/hip_runtime.h>
#include <hip/hip_bf16.h>
#include <math.h>

#define B_  4
#define S_  2048
#define D_  1024
#define H_  16
#define HD_ 64
#define SD_  (S_*D_)        // 2097152
#define SHD_ (S_*HD_)       // 131072

typedef __attribute__((ext_vector_type(8))) short          bf16x8;   // 8 bf16 = 4 VGPRs (MFMA A/B frag)
typedef __attribute__((ext_vector_type(4))) float          f32x4;    // MFMA C/D frag
typedef __attribute__((ext_vector_type(8))) unsigned short ushort8;

__device__ __forceinline__ unsigned short f2bf(float x) {  // RNE float->bf16
  unsigned int u = __float_as_uint(x);
  u += 0x7fffu + ((u >> 16) & 1u);
  return (unsigned short)(u >> 16);
}
__device__ __forceinline__ float bf2f(unsigned short u) {
  return __uint_as_float(((unsigned int)u) << 16);
}

// ---------------------------------------------------------------------------
// GEMM: C = A[8192,1024] @ W[1024,1024]^T + bias, fp32 compute.
// Variant 1: A fp32, out bf16 (Q/K/V projections).
// ---------------------------------------------------------------------------
__global__ __launch_bounds__(256) void gemm_bt_bf16out(
    const float* __restrict__ A, const float* __restrict__ W,
    const float* __restrict__ bias, unsigned short* __restrict__ C)
{
  __shared__ float As[16*128];   // As[kk][m]
  __shared__ float Bs[16*128];   // Bs[kk][n]
  const int tid = threadIdx.x;
  const int tx = tid & 15;
  const int ty = tid >> 4;
  const int n0 = blockIdx.x * 128;
  const int m0 = blockIdx.y * 128;

  float acc[8][8];
#pragma unroll
  for (int i = 0; i < 8; ++i)
#pragma unroll
    for (int j = 0; j < 8; ++j) acc[i][j] = 0.f;

  const float4* A4 = (const float4*)A;
  const float4* W4 = (const float4*)W;

  for (int kt = 0; kt < 64; ++kt) {
#pragma unroll
    for (int uu = 0; uu < 2; ++uu) {
      int u  = tid + uu * 256;
      int r  = u >> 2;
      int c4 = u & 3;
      float4 av = A4[(size_t)(m0 + r) * 256 + kt * 4 + c4];
      As[(4*c4+0)*128 + r] = av.x;
      As[(4*c4+1)*128 + r] = av.y;
      As[(4*c4+2)*128 + r] = av.z;
      As[(4*c4+3)*128 + r] = av.w;
      float4 wv = W4[(size_t)(n0 + r) * 256 + kt * 4 + c4];
      Bs[(4*c4+0)*128 + r] = wv.x;
      Bs[(4*c4+1)*128 + r] = wv.y;
      Bs[(4*c4+2)*128 + r] = wv.z;
      Bs[(4*c4+3)*128 + r] = wv.w;
    }
    __syncthreads();
#pragma unroll
    for (int kk = 0; kk < 16; ++kk) {
      float4 a0 = ((const float4*)As)[kk*32 + ty*2];
      float4 a1 = ((const float4*)As)[kk*32 + ty*2 + 1];
      float4 b0 = ((const float4*)Bs)[kk*32 + tx*2];
      float4 b1 = ((const float4*)Bs)[kk*32 + tx*2 + 1];
      float a[8]  = {a0.x,a0.y,a0.z,a0.w,a1.x,a1.y,a1.z,a1.w};
      float bb[8] = {b0.x,b0.y,b0.z,b0.w,b1.x,b1.y,b1.z,b1.w};
#pragma unroll
      for (int i = 0; i < 8; ++i)
#pragma unroll
        for (int j = 0; j < 8; ++j)
          acc[i][j] = fmaf(a[i], bb[j], acc[i][j]);
    }
    __syncthreads();
  }

#pragma unroll
  for (int i = 0; i < 8; ++i) {
    int row = m0 + ty*8 + i;
    ushort8 ov;
#pragma unroll
    for (int j = 0; j < 8; ++j) ov[j] = f2bf(acc[i][j] + bias[n0 + tx*8 + j]);
    *(ushort8*)&C[(size_t)row*1024 + n0 + tx*8] = ov;
  }
}

// Variant 2: A bf16, out fp32 (O projection).
__global__ __launch_bounds__(256) void gemm_bt_bf16A(
    const unsigned short* __restrict__ A, const float* __restrict__ W,
    const float* __restrict__ bias, float* __restrict__ C)
{
  __shared__ float As[16*128];
  __shared__ float Bs[16*128];
  const int tid = threadIdx.x;
  const int tx = tid & 15;
  const int ty = tid >> 4;
  const int n0 = blockIdx.x * 128;
  const int m0 = blockIdx.y * 128;

  float acc[8][8];
#pragma unroll
  for (int i = 0; i < 8; ++i)
#pragma unroll
    for (int j = 0; j < 8; ++j) acc[i][j] = 0.f;

  const float4* W4 = (const float4*)W;

  for (int kt = 0; kt < 64; ++kt) {
    { // A tile: 128 rows x 16 k (bf16) -> one ushort8 per thread
      int r  = tid >> 1;
      int c8 = tid & 1;
      ushort8 av = *(const ushort8*)&A[(size_t)(m0 + r) * 1024 + kt*16 + c8*8];
#pragma unroll
      for (int e = 0; e < 8; ++e) As[(c8*8+e)*128 + r] = bf2f(av[e]);
    }
#pragma unroll
    for (int uu = 0; uu < 2; ++uu) {
      int u  = tid + uu * 256;
      int r  = u >> 2;
      int c4 = u & 3;
      float4 wv = W4[(size_t)(n0 + r) * 256 + kt * 4 + c4];
      Bs[(4*c4+0)*128 + r] = wv.x;
      Bs[(4*c4+1)*128 + r] = wv.y;
      Bs[(4*c4+2)*128 + r] = wv.z;
      Bs[(4*c4+3)*128 + r] = wv.w;
    }
    __syncthreads();
#pragma unroll
    for (int kk = 0; kk < 16; ++kk) {
      float4 a0 = ((const float4*)As)[kk*32 + ty*2];
      float4 a1 = ((const float4*)As)[kk*32 + ty*2 + 1];
      float4 b0 = ((const float4*)Bs)[kk*32 + tx*2];
      float4 b1 = ((const float4*)Bs)[kk*32 + tx*2 + 1];
      float a[8]  = {a0.x,a0.y,a0.z,a0.w,a1.x,a1.y,a1.z,a1.w};
      float bb[8] = {b0.x,b0.y,b0.z,b0.w,b1.x,b1.y,b1.z,b1.w};
#pragma unroll
      for (int i = 0; i < 8; ++i)
#pragma unroll
        for (int j = 0; j < 8; ++j)
          acc[i][j] = fmaf(a[i], bb[j], acc[i][j]);
    }
    __syncthreads();
  }

  const float4 bv0 = *(const float4*)&bias[n0 + tx*8];
  const float4 bv1 = *(const float4*)&bias[n0 + tx*8 + 4];
#pragma unroll
  for (int i = 0; i < 8; ++i) {
    int row = m0 + ty*8 + i;
    float4 o0 = make_float4(acc[i][0]+bv0.x, acc[i][1]+bv0.y,
                            acc[i][2]+bv0.z, acc[i][3]+bv0.w);
    float4 o1 = make_float4(acc[i][4]+bv1.x, acc[i][5]+bv1.y,
                            acc[i][6]+bv1.z, acc[i][7]+bv1.w);
    ((float4*)C)[(size_t)row*256 + (n0>>2) + tx*2    ] = o0;
    ((float4*)C)[(size_t)row*256 + (n0>>2) + tx*2 + 1] = o1;
  }
}

// ---------------------------------------------------------------------------
// MFMA flash attention. Per (b,h): Q,K,V contiguous [2048,64] bf16 rows.
// WG = 4 waves; wave w owns Q rows [it*64+16w, +16). Per j-tile of 64 keys:
//   QK^T: 4 col-tiles x 2 ksteps of mfma_f32_16x16x32_bf16
//     A-frag (Q): A[m=lane&15][k=quad*8+j]  (preloaded, registers)
//     B-frag (K): K[n=lane&15][k=quad*8+j]  (direct global, row-major fits)
//     C-layout:   col=lane&15, row=quad*4+reg
//   softmax: row-reduce = 4-step shfl_xor over the 16-lane col group
//   P: fp32->bf16 into per-wave LDS strip (C-layout -> A-layout transform)
//   PV: B-frag needs V^T[d][j] -> V staged transposed in LDS (stride 72)
// Output written in place over Qb (each WG owns its 64 rows).
// ---------------------------------------------------------------------------
__global__ __launch_bounds__(256) void attn_mfma(
    unsigned short* __restrict__ Qb, const unsigned short* __restrict__ Kb,
    const unsigned short* __restrict__ Vb, const int* __restrict__ pad)
{
  __shared__ unsigned short Vt[64][72];     // V^T: [d][j], 9216 B
  __shared__ unsigned short Ps[4][16][72];  // per-wave P strip, 9216 B

  const int tid  = threadIdx.x;
  const int lane = tid & 63;
  const int w    = tid >> 6;
  const int it   = blockIdx.x;     // Q tile 0..31
  const int bh   = blockIdx.y;     // 0..63
  const int b    = bh >> 4;
  const size_t base = (size_t)bh * SHD_;

  const int l16  = lane & 15;
  const int quad = lane >> 4;

  // preload Q A-frags (stay in registers for the whole kernel)
  bf16x8 qfrag[2];
  {
    const unsigned short* qrow = Qb + base + (size_t)(it*64 + w*16 + l16) * 64;
    qfrag[0] = *(const bf16x8*)(qrow + quad*8);
    qfrag[1] = *(const bf16x8*)(qrow + 32 + quad*8);
  }

  f32x4 oacc[4];
#pragma unroll
  for (int dt = 0; dt < 4; ++dt) oacc[dt] = (f32x4){0.f,0.f,0.f,0.f};
  float mrow[4], lrow[4];
#pragma unroll
  for (int r = 0; r < 4; ++r) { mrow[r] = -INFINITY; lrow[r] = 0.f; }

  for (int jt = 0; jt <= it; ++jt) {
    __syncthreads();  // all readers of previous Vt done
    // stage V^T (bf16) cooperatively
#pragma unroll
    for (int ii = 0; ii < 2; ++ii) {
      int idx = ii*256 + tid;       // 0..511
      int j   = idx >> 3;           // key 0..63
      int dg  = idx & 7;            // d-group
      ushort8 vv = *(const ushort8*)(Vb + base + (size_t)(jt*64 + j)*64 + dg*8);
#pragma unroll
      for (int e = 0; e < 8; ++e) Vt[dg*8+e][j] = vv[e];
    }
    __syncthreads();

    // ---- QK^T ----
    f32x4 sacc[4];
#pragma unroll
    for (int ct = 0; ct < 4; ++ct) {
      const unsigned short* krow = Kb + base + (size_t)(jt*64 + ct*16 + l16) * 64;
      bf16x8 k0 = *(const bf16x8*)(krow + quad*8);
      bf16x8 k1 = *(const bf16x8*)(krow + 32 + quad*8);
      f32x4 c = (f32x4){0.f,0.f,0.f,0.f};
      c = __builtin_amdgcn_mfma_f32_16x16x32_bf16(qfrag[0], k0, c, 0, 0, 0);
      c = __builtin_amdgcn_mfma_f32_16x16x32_bf16(qfrag[1], k1, c, 0, 0, 0);
      sacc[ct] = c;
    }

    // ---- masked online softmax ----
    int padv[4];
#pragma unroll
    for (int ct = 0; ct < 4; ++ct) padv[ct] = pad[b*S_ + jt*64 + ct*16 + l16];

    const int grow0 = it*64 + w*16 + quad*4;
    float alpha[4];
    float p[4][4];   // [reg][ct]
#pragma unroll
    for (int reg = 0; reg < 4; ++reg) {
      const int gi = grow0 + reg;
      float lg[4];
      float mx = -INFINITY;
#pragma unroll
      for (int ct = 0; ct < 4; ++ct) {
        int gj = jt*64 + ct*16 + l16;
        bool ok = (gj <= gi) && (padv[ct] != 0);
        lg[ct] = ok ? sacc[ct][reg] * 0.125f : -INFINITY;
        mx = fmaxf(mx, lg[ct]);
      }
#pragma unroll
      for (int off = 1; off < 16; off <<= 1) mx = fmaxf(mx, __shfl_xor(mx, off, 64));
      float mnew = fmaxf(mrow[reg], mx);
      float a    = __expf(mrow[reg] - mnew);   // 0 on first tile (m=-inf)
      float sm   = 0.f;
#pragma unroll
      for (int ct = 0; ct < 4; ++ct) {
        float pe = __expf(lg[ct] - mnew);      // masked -> exp(-inf)=0
        p[reg][ct] = pe;
        sm += pe;
      }
#pragma unroll
      for (int off = 1; off < 16; off <<= 1) sm += __shfl_xor(sm, off, 64);
      lrow[reg]  = lrow[reg]*a + sm;
      mrow[reg]  = mnew;
      alpha[reg] = a;
    }
#pragma unroll
    for (int dt = 0; dt < 4; ++dt)
#pragma unroll
      for (int reg = 0; reg < 4; ++reg) oacc[dt][reg] *= alpha[reg];

    // ---- P: C-layout -> A-layout via per-wave LDS strip ----
#pragma unroll
    for (int reg = 0; reg < 4; ++reg)
#pragma unroll
      for (int ct = 0; ct < 4; ++ct)
        Ps[w][quad*4 + reg][ct*16 + l16] = f2bf(p[reg][ct]);
    // same-wave LDS RAW: compiler inserts lgkmcnt wait; no barrier needed.

    bf16x8 pfrag0 = *(const bf16x8*)&Ps[w][l16][quad*8];
    bf16x8 pfrag1 = *(const bf16x8*)&Ps[w][l16][32 + quad*8];

    // ---- PV ----
#pragma unroll
    for (int dt = 0; dt < 4; ++dt) {
      bf16x8 v0 = *(const bf16x8*)&Vt[dt*16 + l16][quad*8];
      bf16x8 v1 = *(const bf16x8*)&Vt[dt*16 + l16][32 + quad*8];
      oacc[dt] = __builtin_amdgcn_mfma_f32_16x16x32_bf16(pfrag0, v0, oacc[dt], 0, 0, 0);
      oacc[dt] = __builtin_amdgcn_mfma_f32_16x16x32_bf16(pfrag1, v1, oacc[dt], 0, 0, 0);
    }
  }

  // epilogue: normalize, write bf16 in place over Qb (own rows only)
#pragma unroll
  for (int reg = 0; reg < 4; ++reg) {
    const float rl = 1.0f / lrow[reg];
    unsigned short* orow = Qb + base + (size_t)(it*64 + w*16 + quad*4 + reg) * 64;
#pragma unroll
    for (int dt = 0; dt < 4; ++dt)
      orow[dt*16 + l16] = f2bf(oacc[dt][reg] * rl);
  }
}

// ---------------------------------------------------------------------------
// Residual + LayerNorm (unchanged from round 1)
// ---------------------------------------------------------------------------
__global__ __launch_bounds__(256) void ln_kernel(
    const float* __restrict__ x, const float* __restrict__ O,
    const float* __restrict__ gamma, const float* __restrict__ beta,
    float* __restrict__ out)
{
  __shared__ float red[8];
  const int row = blockIdx.x;
  const int tid = threadIdx.x;
  float4 xv = ((const float4*)x)[(size_t)row*256 + tid];
  float4 ov = ((const float4*)O)[(size_t)row*256 + tid];
  float4 y  = make_float4(xv.x+ov.x, xv.y+ov.y, xv.z+ov.z, xv.w+ov.w);
  float s1 = y.x + y.y + y.z + y.w;
  float s2 = y.x*y.x + y.y*y.y + y.z*y.z + y.w*y.w;
#pragma unroll
  for (int off = 32; off >= 1; off >>= 1) {
    s1 += __shfl_xor(s1, off, 64);
    s2 += __shfl_xor(s2, off, 64);
  }
  if ((tid & 63) == 0) { red[tid>>6] = s1; red[4 + (tid>>6)] = s2; }
  __syncthreads();
  s1 = red[0] + red[1] + red[2] + red[3];
  s2 = red[4] + red[5] + red[6] + red[7];
  const float mean = s1 * (1.0f/1024.0f);
  const float var  = fmaxf(s2 * (1.0f/1024.0f) - mean*mean, 0.f);
  const float rstd = 1.0f / (sqrtf(var) + 1e-8f);
  float4 gv = ((const float4*)gamma)[tid];
  float4 bv = ((const float4*)beta)[tid];
  float4 r;
  r.x = gv.x*(y.x-mean)*rstd + bv.x;
  r.y = gv.y*(y.y-mean)*rstd + bv.y;
  r.z = gv.z*(y.z-mean)*rstd + bv.z;
  r.w = gv.w*(y.w-mean)*rstd + bv.w;
  ((float4*)out)[(size_t)row*256 + tid] = r;
}

// ---------------------------------------------------------------------------
extern "C" void kernel_launch(void* const* d_in, const int* in_sizes, int n_in,
                              void* d_out, int out_size, void* d_ws, size_t ws_size,
                              hipStream_t stream)
{
  const float* q  = (const float*)d_in[0];
  const float* k  = (const float*)d_in[1];
  const float* v  = (const float*)d_in[2];
  // d_in[3] = causal tril mask — applied analytically (j<=i)
  const int*   pad = (const int*)d_in[4];
  const float* Wq = (const float*)d_in[5];
  const float* bq = (const float*)d_in[6];
  const float* Wk = (const float*)d_in[7];
  const float* bk = (const float*)d_in[8];
  const float* Wv = (const float*)d_in[9];
  const float* bv = (const float*)d_in[10];
  const float* Wo = (const float*)d_in[11];
  const float* bo = (const float*)d_in[12];
  const float* gamma = (const float*)d_in[13];
  const float* beta  = (const float*)d_in[14];
  float* out = (float*)d_out;

  char* ws = (char*)d_ws;
  float*          Obuf = (float*)ws;                                   // 32 MB fp32
  unsigned short* Qb   = (unsigned short*)(ws + (size_t)32*1024*1024); // 16 MB bf16
  unsigned short* Kb   = (unsigned short*)(ws + (size_t)48*1024*1024); // 16 MB
  unsigned short* Vb   = (unsigned short*)(ws + (size_t)64*1024*1024); // 16 MB

  dim3 gg(8, 64), bb(256);
  gemm_bt_bf16out<<<gg, bb, 0, stream>>>(q, Wq, bq, Qb);
  gemm_bt_bf16out<<<gg, bb, 0, stream>>>(k, Wk, bk, Kb);
  gemm_bt_bf16out<<<gg, bb, 0, stream>>>(v, Wv, bv, Vb);
  attn_mfma<<<dim3(32, 64), 256, 0, stream>>>(Qb, Kb, Vb, pad);   // Qb <- attn out (bf16, in place)
  gemm_bt_bf16A<<<gg, bb, 0, stream>>>(Qb, Wo, bo, Obuf);         // Obuf <- O projection (fp32)
  ln_kernel<<<dim3(B_*S_), 256, 0, stream>>>(q, Obuf, gamma, beta, out);
}

// Round 4
// 778.508 us; speedup vs baseline: 4.7475x; 1.7910x over previous
//
#include <hip/hip_runtime.h>
#include <hip/hip_bf16.h>
#include <math.h>

#define B_  4
#define S_  2048
#define D_  1024
#define H_  16
#define HD_ 64
#define SD_  (S_*D_)        // 2097152
#define SHD_ (S_*HD_)       // 131072

typedef __attribute__((ext_vector_type(8))) short          bf16x8;   // MFMA A/B frag (4 VGPRs)
typedef __attribute__((ext_vector_type(4))) float          f32x4;    // MFMA C/D frag
typedef __attribute__((ext_vector_type(8))) unsigned short us8;
typedef __attribute__((ext_vector_type(4))) unsigned short us4;

__device__ __forceinline__ unsigned short f2bf(float x) {  // RNE float->bf16
  unsigned int u = __float_as_uint(x);
  u += 0x7fffu + ((u >> 16) & 1u);
  return (unsigned short)(u >> 16);
}
__device__ __forceinline__ float bf2f(unsigned short u) {
  return __uint_as_float(((unsigned int)u) << 16);
}

// async global->LDS, 16B per lane: wave-uniform LDS base + lane*16 (m104).
__device__ __forceinline__ void gload16(const unsigned short* g, unsigned short* l) {
  __builtin_amdgcn_global_load_lds(
      (const __attribute__((address_space(1))) unsigned int*)g,
      (__attribute__((address_space(3))) unsigned int*)l,
      16, 0, 0);
}

// ---------------------------------------------------------------------------
// fp32 -> bf16 converts
// ---------------------------------------------------------------------------
__global__ __launch_bounds__(256) void cvt_a(const float* __restrict__ s,
                                             unsigned short* __restrict__ d)
{
  int i = blockIdx.x * 256 + threadIdx.x;          // float4 index
  float4 v = ((const float4*)s)[i];
  us4 o = { f2bf(v.x), f2bf(v.y), f2bf(v.z), f2bf(v.w) };
  *(us4*)(d + (size_t)i * 4) = o;
}

__global__ __launch_bounds__(256) void cvt_w(const float* __restrict__ w0,
                                             const float* __restrict__ w1,
                                             const float* __restrict__ w2,
                                             const float* __restrict__ w3,
                                             unsigned short* __restrict__ dst)
{
  const float* s = (blockIdx.y == 0) ? w0 : (blockIdx.y == 1) ? w1
                 : (blockIdx.y == 2) ? w2 : w3;
  unsigned short* d = dst + (size_t)blockIdx.y * 1024 * 1024;
  int i = blockIdx.x * 256 + threadIdx.x;
  float4 v = ((const float4*)s)[i];
  us4 o = { f2bf(v.x), f2bf(v.y), f2bf(v.z), f2bf(v.w) };
  *(us4*)(d + (size_t)i * 4) = o;
}

// ---------------------------------------------------------------------------
// bf16 MFMA GEMM (m97 structure): C[8192,1024] = A @ W^T + bias, bf16 out
// (flat row-major — correct for the reference's flat head-view by construction).
// 128x128 tile, BK=32, 256 thr = 4 waves (2x2), 4x4 16x16 tiles per wave.
// ---------------------------------------------------------------------------
__global__ __launch_bounds__(256) void gemm_mfma(
    const unsigned short* __restrict__ A,    // [8192,1024] bf16
    const unsigned short* __restrict__ Wb,   // [1024,1024] bf16, row n = out col
    const float* __restrict__ bias,
    unsigned short* __restrict__ Cb)
{
  __shared__ unsigned short As[128 * 32];   // [row][k] 8 KB
  __shared__ unsigned short Bs[128 * 32];   // [ncol][k] 8 KB

  const int tid  = threadIdx.x;
  const int lane = tid & 63;
  const int w    = tid >> 6;
  const int wm   = w >> 1, wn = w & 1;
  const int l16  = lane & 15, quad = lane >> 4;
  const int n0 = blockIdx.x * 128;
  const int m0 = blockIdx.y * 128;

  f32x4 acc[4][4];
#pragma unroll
  for (int mt = 0; mt < 4; ++mt)
#pragma unroll
    for (int nt = 0; nt < 4; ++nt) acc[mt][nt] = (f32x4){0.f, 0.f, 0.f, 0.f};

  const int srow = lane >> 2;          // 0..15 row within 16-row slab
  const int sseg = (lane & 3) * 8;     // ushort offset within 32-elem row

  for (int kt = 0; kt < 32; ++kt) {
    const int kofs = kt * 32;
#pragma unroll
    for (int t = 0; t < 2; ++t) {
      const int r = w * 32 + t * 16 + srow;          // 0..127
      gload16(A  + (size_t)(m0 + r) * 1024 + kofs + sseg, &As[r * 32 + sseg]);
      gload16(Wb + (size_t)(n0 + r) * 1024 + kofs + sseg, &Bs[r * 32 + sseg]);
    }
    __syncthreads();   // drains vmcnt (global_load_lds) + barrier

    bf16x8 af[4], bfr[4];
#pragma unroll
    for (int mt = 0; mt < 4; ++mt)
      af[mt] = *(const bf16x8*)&As[(wm * 64 + mt * 16 + l16) * 32 + quad * 8];
#pragma unroll
    for (int nt = 0; nt < 4; ++nt)
      bfr[nt] = *(const bf16x8*)&Bs[(wn * 64 + nt * 16 + l16) * 32 + quad * 8];
#pragma unroll
    for (int mt = 0; mt < 4; ++mt)
#pragma unroll
      for (int nt = 0; nt < 4; ++nt)
        acc[mt][nt] = __builtin_amdgcn_mfma_f32_16x16x32_bf16(
            af[mt], bfr[nt], acc[mt][nt], 0, 0, 0);
    __syncthreads();   // frag reads done before next stage overwrites
  }

  // C-layout: col=l16, row=quad*4+reg  (m89-verified)
#pragma unroll
  for (int nt = 0; nt < 4; ++nt) {
    const int ncol = n0 + wn * 64 + nt * 16 + l16;
    const float bv = bias[ncol];
#pragma unroll
    for (int mt = 0; mt < 4; ++mt) {
      const int row = m0 + wm * 64 + mt * 16 + quad * 4;
#pragma unroll
      for (int reg = 0; reg < 4; ++reg)
        Cb[(size_t)(row + reg) * 1024 + ncol] = f2bf(acc[mt][nt][reg] + bv);
    }
  }
}

// ---------------------------------------------------------------------------
// V transpose: Vt[bh][d][s] = Vflat[bh*131072 + s*64 + d]  (pure flat indices,
// so the reference's scrambled head-view is handled automatically).
// One block per (s-tile of 64, bh). 8 KB in (contiguous), 8 KB out.
// ---------------------------------------------------------------------------
__global__ __launch_bounds__(256) void vtrans(
    const unsigned short* __restrict__ V, unsigned short* __restrict__ Vt)
{
  __shared__ unsigned short t[64][72];   // t[s][d], padded rows (144 B, 16B-aligned)
  const int tid = threadIdx.x;
  const int st  = blockIdx.x;            // s-tile 0..31
  const int bh  = blockIdx.y;            // 0..63
  const unsigned short* src = V + (size_t)bh * SHD_ + (size_t)st * 4096;

#pragma unroll
  for (int u = tid; u < 512; u += 256) {           // 512 us8 chunks = 8 KB
    us8 vv = ((const us8*)src)[u];
    int s  = u >> 3;                               // 8 chunks per 64-elem s-row
    int dg = (u & 7) * 8;
    *(us8*)&t[s][dg] = vv;                         // 16B-aligned LDS write
  }
  __syncthreads();

  unsigned short* dst = Vt + (size_t)bh * SHD_ + st * 64;
#pragma unroll
  for (int u = tid; u < 1024; u += 256) {          // 64 d-rows x 16 us4 chunks
    int d  = u >> 4;
    int s4 = (u & 15) * 4;
    us4 o = { t[s4][d], t[s4 + 1][d], t[s4 + 2][d], t[s4 + 3][d] };
    *(us4*)(dst + (size_t)d * 2048 + s4) = o;
  }
}

// ---------------------------------------------------------------------------
// Barrier-free MFMA flash attention (unchanged from round 3).
// Per (b,h): Q,K flat [2048,64] bf16 rows; V^T [64,2048].
// WG = 4 waves; wave w owns Q rows it*64+w*16..+15, fully independent.
// ---------------------------------------------------------------------------
__global__ __launch_bounds__(256) void attn_mfma(
    unsigned short* __restrict__ Qb, const unsigned short* __restrict__ Kb,
    const unsigned short* __restrict__ Vt, const int* __restrict__ pad)
{
  __shared__ unsigned short Ps[4][16][72];  // per-wave P strip, 9216 B

  const int tid  = threadIdx.x;
  const int lane = tid & 63;
  const int w    = tid >> 6;
  const int it   = blockIdx.x;     // Q tile 0..31
  const int bh   = blockIdx.y;     // 0..63
  const int b    = bh >> 4;
  const size_t base = (size_t)bh * SHD_;

  const int l16  = lane & 15;
  const int quad = lane >> 4;

  bf16x8 qfrag[2];
  {
    const unsigned short* qrow = Qb + base + (size_t)(it * 64 + w * 16 + l16) * 64;
    qfrag[0] = *(const bf16x8*)(qrow + quad * 8);
    qfrag[1] = *(const bf16x8*)(qrow + 32 + quad * 8);
  }

  f32x4 oacc[4];
#pragma unroll
  for (int dt = 0; dt < 4; ++dt) oacc[dt] = (f32x4){0.f, 0.f, 0.f, 0.f};
  float mrow[4], lrow[4];
#pragma unroll
  for (int r = 0; r < 4; ++r) { mrow[r] = -INFINITY; lrow[r] = 0.f; }

  for (int jt = 0; jt <= it; ++jt) {
    // ---- QK^T (K B-frags direct from global) ----
    f32x4 sacc[4];
#pragma unroll
    for (int ct = 0; ct < 4; ++ct) {
      const unsigned short* krow = Kb + base + (size_t)(jt * 64 + ct * 16 + l16) * 64;
      bf16x8 k0 = *(const bf16x8*)(krow + quad * 8);
      bf16x8 k1 = *(const bf16x8*)(krow + 32 + quad * 8);
      f32x4 c = (f32x4){0.f, 0.f, 0.f, 0.f};
      c = __builtin_amdgcn_mfma_f32_16x16x32_bf16(qfrag[0], k0, c, 0, 0, 0);
      c = __builtin_amdgcn_mfma_f32_16x16x32_bf16(qfrag[1], k1, c, 0, 0, 0);
      sacc[ct] = c;
    }

    // ---- masked online softmax (C-layout: row=quad*4+reg, col=ct*16+l16) ----
    int padv[4];
#pragma unroll
    for (int ct = 0; ct < 4; ++ct) padv[ct] = pad[b * S_ + jt * 64 + ct * 16 + l16];

    const int grow0 = it * 64 + w * 16 + quad * 4;
    float alpha[4];
    float p[4][4];
#pragma unroll
    for (int reg = 0; reg < 4; ++reg) {
      const int gi = grow0 + reg;
      float lg[4];
      float mx = -INFINITY;
#pragma unroll
      for (int ct = 0; ct < 4; ++ct) {
        int gj = jt * 64 + ct * 16 + l16;
        bool ok = (gj <= gi) && (padv[ct] != 0);
        lg[ct] = ok ? sacc[ct][reg] * 0.125f : -INFINITY;
        mx = fmaxf(mx, lg[ct]);
      }
#pragma unroll
      for (int off = 1; off < 16; off <<= 1) mx = fmaxf(mx, __shfl_xor(mx, off, 64));
      float mnew = fmaxf(mrow[reg], mx);
      float a    = __expf(mrow[reg] - mnew);
      float sm   = 0.f;
#pragma unroll
      for (int ct = 0; ct < 4; ++ct) {
        float pe = __expf(lg[ct] - mnew);
        p[reg][ct] = pe;
        sm += pe;
      }
#pragma unroll
      for (int off = 1; off < 16; off <<= 1) sm += __shfl_xor(sm, off, 64);
      lrow[reg]  = lrow[reg] * a + sm;
      mrow[reg]  = mnew;
      alpha[reg] = a;
    }
#pragma unroll
    for (int dt = 0; dt < 4; ++dt)
#pragma unroll
      for (int reg = 0; reg < 4; ++reg) oacc[dt][reg] *= alpha[reg];

    // ---- P: C-layout -> A-layout via per-wave LDS strip (no barrier) ----
#pragma unroll
    for (int reg = 0; reg < 4; ++reg)
#pragma unroll
      for (int ct = 0; ct < 4; ++ct)
        Ps[w][quad * 4 + reg][ct * 16 + l16] = f2bf(p[reg][ct]);

    bf16x8 pfrag0 = *(const bf16x8*)&Ps[w][l16][quad * 8];
    bf16x8 pfrag1 = *(const bf16x8*)&Ps[w][l16][32 + quad * 8];

    // ---- PV (V^T B-frags direct from global) ----
#pragma unroll
    for (int dt = 0; dt < 4; ++dt) {
      const unsigned short* vrow = Vt + base + (size_t)(dt * 16 + l16) * 2048 + jt * 64;
      bf16x8 v0 = *(const bf16x8*)(vrow + quad * 8);
      bf16x8 v1 = *(const bf16x8*)(vrow + 32 + quad * 8);
      oacc[dt] = __builtin_amdgcn_mfma_f32_16x16x32_bf16(pfrag0, v0, oacc[dt], 0, 0, 0);
      oacc[dt] = __builtin_amdgcn_mfma_f32_16x16x32_bf16(pfrag1, v1, oacc[dt], 0, 0, 0);
    }
  }

  // epilogue: normalize, write bf16 in place over Qb (own rows only)
#pragma unroll
  for (int reg = 0; reg < 4; ++reg) {
    const float rl = 1.0f / lrow[reg];
    unsigned short* orow = Qb + base + (size_t)(it * 64 + w * 16 + quad * 4 + reg) * 64;
#pragma unroll
    for (int dt = 0; dt < 4; ++dt)
      orow[dt * 16 + l16] = f2bf(oacc[dt][reg] * rl);
  }
}

// ---------------------------------------------------------------------------
// Residual + LayerNorm; O is bf16.
// ---------------------------------------------------------------------------
__global__ __launch_bounds__(256) void ln_kernel(
    const float* __restrict__ x, const unsigned short* __restrict__ O,
    const float* __restrict__ gamma, const float* __restrict__ beta,
    float* __restrict__ out)
{
  __shared__ float red[8];
  const int row = blockIdx.x;
  const int tid = threadIdx.x;
  float4 xv = ((const float4*)x)[(size_t)row * 256 + tid];
  us4 ov4 = *(const us4*)(O + (size_t)row * 1024 + tid * 4);
  float4 y = make_float4(xv.x + bf2f(ov4[0]), xv.y + bf2f(ov4[1]),
                         xv.z + bf2f(ov4[2]), xv.w + bf2f(ov4[3]));
  float s1 = y.x + y.y + y.z + y.w;
  float s2 = y.x*y.x + y.y*y.y + y.z*y.z + y.w*y.w;
#pragma unroll
  for (int off = 32; off >= 1; off >>= 1) {
    s1 += __shfl_xor(s1, off, 64);
    s2 += __shfl_xor(s2, off, 64);
  }
  if ((tid & 63) == 0) { red[tid >> 6] = s1; red[4 + (tid >> 6)] = s2; }
  __syncthreads();
  s1 = red[0] + red[1] + red[2] + red[3];
  s2 = red[4] + red[5] + red[6] + red[7];
  const float mean = s1 * (1.0f / 1024.0f);
  const float var  = fmaxf(s2 * (1.0f / 1024.0f) - mean * mean, 0.f);
  const float rstd = 1.0f / (sqrtf(var) + 1e-8f);
  float4 gv = ((const float4*)gamma)[tid];
  float4 bv = ((const float4*)beta)[tid];
  float4 r;
  r.x = gv.x * (y.x - mean) * rstd + bv.x;
  r.y = gv.y * (y.y - mean) * rstd + bv.y;
  r.z = gv.z * (y.z - mean) * rstd + bv.z;
  r.w = gv.w * (y.w - mean) * rstd + bv.w;
  ((float4*)out)[(size_t)row * 256 + tid] = r;
}

// ---------------------------------------------------------------------------
extern "C" void kernel_launch(void* const* d_in, const int* in_sizes, int n_in,
                              void* d_out, int out_size, void* d_ws, size_t ws_size,
                              hipStream_t stream)
{
  const float* q  = (const float*)d_in[0];
  const float* k  = (const float*)d_in[1];
  const float* v  = (const float*)d_in[2];
  // d_in[3] = causal tril mask — applied analytically (j<=i)
  const int*   pad = (const int*)d_in[4];
  const float* Wq = (const float*)d_in[5];
  const float* bq = (const float*)d_in[6];
  const float* Wk = (const float*)d_in[7];
  const float* bk = (const float*)d_in[8];
  const float* Wv = (const float*)d_in[9];
  const float* bv = (const float*)d_in[10];
  const float* Wo = (const float*)d_in[11];
  const float* bo = (const float*)d_in[12];
  const float* gamma = (const float*)d_in[13];
  const float* beta  = (const float*)d_in[14];
  float* out = (float*)d_out;

  char* ws = (char*)d_ws;
  const size_t MB = 1024 * 1024;
  unsigned short* Ac   = (unsigned short*)(ws);             // 16 MB bf16 staging
  unsigned short* Qb   = (unsigned short*)(ws + 16 * MB);   // 16 MB
  unsigned short* Kb   = (unsigned short*)(ws + 32 * MB);   // 16 MB
  unsigned short* Vb   = (unsigned short*)(ws + 48 * MB);   // 16 MB (flat V)
  unsigned short* Vtb  = (unsigned short*)(ws + 64 * MB);   // 16 MB (V^T per bh)
  unsigned short* Wall = (unsigned short*)(ws + 80 * MB);   // 8 MB (4 weights bf16)
  unsigned short* Obuf = Ac;                                // alias: Ac dead after V-GEMM

  dim3 gg(8, 64), bb(256);
  cvt_w<<<dim3(1024, 4), 256, 0, stream>>>(Wq, Wk, Wv, Wo, Wall);

  cvt_a<<<8192, 256, 0, stream>>>(q, Ac);
  gemm_mfma<<<gg, bb, 0, stream>>>(Ac, Wall + 0 * MB, bq, Qb);
  cvt_a<<<8192, 256, 0, stream>>>(k, Ac);
  gemm_mfma<<<gg, bb, 0, stream>>>(Ac, Wall + 1 * MB, bk, Kb);
  cvt_a<<<8192, 256, 0, stream>>>(v, Ac);
  gemm_mfma<<<gg, bb, 0, stream>>>(Ac, Wall + 2 * MB, bv, Vb);
  vtrans<<<dim3(32, 64), 256, 0, stream>>>(Vb, Vtb);

  attn_mfma<<<dim3(32, 64), 256, 0, stream>>>(Qb, Kb, Vtb, pad);  // Qb <- attn out

  gemm_mfma<<<gg, bb, 0, stream>>>(Qb, Wall + 3 * MB, bo, Obuf);
  ln_kernel<<<dim3(B_ * S_), 256, 0, stream>>>(q, Obuf, gamma, beta, out);
}

// Round 5
// 559.513 us; speedup vs baseline: 6.6057x; 1.3914x over previous
//
#include <hip/hip_runtime.h>
#include <hip/hip_bf16.h>
#include <math.h>

#define B_  4
#define S_  2048
#define D_  1024
#define H_  16
#define HD_ 64
#define SD_  (S_*D_)        // 2097152
#define SHD_ (S_*HD_)       // 131072

typedef __attribute__((ext_vector_type(8))) short          bf16x8;   // MFMA A/B frag (4 VGPRs)
typedef __attribute__((ext_vector_type(4))) float          f32x4;    // MFMA C/D frag
typedef __attribute__((ext_vector_type(8))) unsigned short us8;
typedef __attribute__((ext_vector_type(4))) unsigned short us4;

__device__ __forceinline__ unsigned short f2bf(float x) {  // RNE float->bf16
  unsigned int u = __float_as_uint(x);
  u += 0x7fffu + ((u >> 16) & 1u);
  return (unsigned short)(u >> 16);
}
__device__ __forceinline__ float bf2f(unsigned short u) {
  return __uint_as_float(((unsigned int)u) << 16);
}

// async global->LDS, 16B per lane: wave-uniform LDS base + lane*16 (m104).
__device__ __forceinline__ void gload16(const unsigned short* g, unsigned short* l) {
  __builtin_amdgcn_global_load_lds(
      (const __attribute__((address_space(1))) unsigned int*)g,
      (__attribute__((address_space(3))) unsigned int*)l,
      16, 0, 0);
}

// ---------------------------------------------------------------------------
// fp32 -> bf16 converts
// ---------------------------------------------------------------------------
__global__ __launch_bounds__(256) void cvt_a(const float* __restrict__ s,
                                             unsigned short* __restrict__ d)
{
  int i = blockIdx.x * 256 + threadIdx.x;          // float4 index
  float4 v = ((const float4*)s)[i];
  us4 o = { f2bf(v.x), f2bf(v.y), f2bf(v.z), f2bf(v.w) };
  *(us4*)(d + (size_t)i * 4) = o;
}

__global__ __launch_bounds__(256) void cvt_w(const float* __restrict__ w0,
                                             const float* __restrict__ w1,
                                             const float* __restrict__ w2,
                                             const float* __restrict__ w3,
                                             unsigned short* __restrict__ dst)
{
  const float* s = (blockIdx.y == 0) ? w0 : (blockIdx.y == 1) ? w1
                 : (blockIdx.y == 2) ? w2 : w3;
  unsigned short* d = dst + (size_t)blockIdx.y * 1024 * 1024;
  int i = blockIdx.x * 256 + threadIdx.x;
  float4 v = ((const float4*)s)[i];
  us4 o = { f2bf(v.x), f2bf(v.y), f2bf(v.z), f2bf(v.w) };
  *(us4*)(d + (size_t)i * 4) = o;
}

// ---------------------------------------------------------------------------
// bf16 MFMA GEMM (m97 structure): C[8192,1024] = A @ W^T + bias, bf16 out
// (flat row-major — correct for the reference's flat head-view by construction).
// 128x128 tile, BK=32, 256 thr = 4 waves (2x2), 4x4 16x16 tiles per wave.
// ---------------------------------------------------------------------------
__global__ __launch_bounds__(256) void gemm_mfma(
    const unsigned short* __restrict__ A,    // [8192,1024] bf16
    const unsigned short* __restrict__ Wb,   // [1024,1024] bf16, row n = out col
    const float* __restrict__ bias,
    unsigned short* __restrict__ Cb)
{
  __shared__ unsigned short As[128 * 32];   // [row][k] 8 KB
  __shared__ unsigned short Bs[128 * 32];   // [ncol][k] 8 KB

  const int tid  = threadIdx.x;
  const int lane = tid & 63;
  const int w    = tid >> 6;
  const int wm   = w >> 1, wn = w & 1;
  const int l16  = lane & 15, quad = lane >> 4;
  const int n0 = blockIdx.x * 128;
  const int m0 = blockIdx.y * 128;

  f32x4 acc[4][4];
#pragma unroll
  for (int mt = 0; mt < 4; ++mt)
#pragma unroll
    for (int nt = 0; nt < 4; ++nt) acc[mt][nt] = (f32x4){0.f, 0.f, 0.f, 0.f};

  const int srow = lane >> 2;          // 0..15 row within 16-row slab
  const int sseg = (lane & 3) * 8;     // ushort offset within 32-elem row

  for (int kt = 0; kt < 32; ++kt) {
    const int kofs = kt * 32;
#pragma unroll
    for (int t = 0; t < 2; ++t) {
      const int r = w * 32 + t * 16 + srow;          // 0..127
      gload16(A  + (size_t)(m0 + r) * 1024 + kofs + sseg, &As[r * 32 + sseg]);
      gload16(Wb + (size_t)(n0 + r) * 1024 + kofs + sseg, &Bs[r * 32 + sseg]);
    }
    __syncthreads();   // drains vmcnt (global_load_lds) + barrier

    bf16x8 af[4], bfr[4];
#pragma unroll
    for (int mt = 0; mt < 4; ++mt)
      af[mt] = *(const bf16x8*)&As[(wm * 64 + mt * 16 + l16) * 32 + quad * 8];
#pragma unroll
    for (int nt = 0; nt < 4; ++nt)
      bfr[nt] = *(const bf16x8*)&Bs[(wn * 64 + nt * 16 + l16) * 32 + quad * 8];
#pragma unroll
    for (int mt = 0; mt < 4; ++mt)
#pragma unroll
      for (int nt = 0; nt < 4; ++nt)
        acc[mt][nt] = __builtin_amdgcn_mfma_f32_16x16x32_bf16(
            af[mt], bfr[nt], acc[mt][nt], 0, 0, 0);
    __syncthreads();   // frag reads done before next stage overwrites
  }

  // C-layout: col=l16, row=quad*4+reg  (m89-verified)
#pragma unroll
  for (int nt = 0; nt < 4; ++nt) {
    const int ncol = n0 + wn * 64 + nt * 16 + l16;
    const float bv = bias[ncol];
#pragma unroll
    for (int mt = 0; mt < 4; ++mt) {
      const int row = m0 + wm * 64 + mt * 16 + quad * 4;
#pragma unroll
      for (int reg = 0; reg < 4; ++reg)
        Cb[(size_t)(row + reg) * 1024 + ncol] = f2bf(acc[mt][nt][reg] + bv);
    }
  }
}

// ---------------------------------------------------------------------------
// V transpose: Vt[bh][d][s] = Vflat[bh*131072 + s*64 + d]  (pure flat indices,
// so the reference's scrambled head-view is handled automatically).
// ---------------------------------------------------------------------------
__global__ __launch_bounds__(256) void vtrans(
    const unsigned short* __restrict__ V, unsigned short* __restrict__ Vt)
{
  __shared__ unsigned short t[64][72];   // t[s][d], padded rows
  const int tid = threadIdx.x;
  const int st  = blockIdx.x;            // s-tile 0..31
  const int bh  = blockIdx.y;            // 0..63
  const unsigned short* src = V + (size_t)bh * SHD_ + (size_t)st * 4096;

#pragma unroll
  for (int u = tid; u < 512; u += 256) {           // 512 us8 chunks = 8 KB
    us8 vv = ((const us8*)src)[u];
    int s  = u >> 3;
    int dg = (u & 7) * 8;
    *(us8*)&t[s][dg] = vv;
  }
  __syncthreads();

  unsigned short* dst = Vt + (size_t)bh * SHD_ + st * 64;
#pragma unroll
  for (int u = tid; u < 1024; u += 256) {          // 64 d-rows x 16 us4 chunks
    int d  = u >> 4;
    int s4 = (u & 15) * 4;
    us4 o = { t[s4][d], t[s4 + 1][d], t[s4 + 2][d], t[s4 + 3][d] };
    *(us4*)(dst + (size_t)d * 2048 + s4) = o;
  }
}

// ---------------------------------------------------------------------------
// Barrier-free MFMA flash attention with DIAGONAL PAIRING for load balance.
// WG p (0..15) processes Q-tiles {p, 31-p}: every WG does exactly 33
// j-iterations -> no triangular tail, all 1024 WGs (4/CU) busy throughout.
// Per (b,h): Q,K flat [2048,64] bf16 rows; V^T [64,2048].
// V^T frag loads issued BEFORE the softmax VALU chain (latency overlap).
// ---------------------------------------------------------------------------
__global__ __launch_bounds__(256, 4) void attn_mfma(
    unsigned short* __restrict__ Qb, const unsigned short* __restrict__ Kb,
    const unsigned short* __restrict__ Vt, const int* __restrict__ pad)
{
  __shared__ unsigned short Ps[4][16][72];  // per-wave P strip, 9216 B

  const int tid  = threadIdx.x;
  const int lane = tid & 63;
  const int w    = tid >> 6;
  const int p    = blockIdx.x;     // pair index 0..15
  const int bh   = blockIdx.y;     // 0..63
  const int b    = bh >> 4;
  const size_t base = (size_t)bh * SHD_;

  const int l16  = lane & 15;
  const int quad = lane >> 4;

  for (int half = 0; half < 2; ++half) {
    const int it = half ? (31 - p) : p;

    bf16x8 qfrag[2];
    {
      const unsigned short* qrow = Qb + base + (size_t)(it * 64 + w * 16 + l16) * 64;
      qfrag[0] = *(const bf16x8*)(qrow + quad * 8);
      qfrag[1] = *(const bf16x8*)(qrow + 32 + quad * 8);
    }

    f32x4 oacc[4];
#pragma unroll
    for (int dt = 0; dt < 4; ++dt) oacc[dt] = (f32x4){0.f, 0.f, 0.f, 0.f};
    float mrow[4], lrow[4];
#pragma unroll
    for (int r = 0; r < 4; ++r) { mrow[r] = -INFINITY; lrow[r] = 0.f; }

    for (int jt = 0; jt <= it; ++jt) {
      // ---- QK^T (K B-frags direct from global, L2-hot) ----
      f32x4 sacc[4];
#pragma unroll
      for (int ct = 0; ct < 4; ++ct) {
        const unsigned short* krow = Kb + base + (size_t)(jt * 64 + ct * 16 + l16) * 64;
        bf16x8 k0 = *(const bf16x8*)(krow + quad * 8);
        bf16x8 k1 = *(const bf16x8*)(krow + 32 + quad * 8);
        f32x4 c = (f32x4){0.f, 0.f, 0.f, 0.f};
        c = __builtin_amdgcn_mfma_f32_16x16x32_bf16(qfrag[0], k0, c, 0, 0, 0);
        c = __builtin_amdgcn_mfma_f32_16x16x32_bf16(qfrag[1], k1, c, 0, 0, 0);
        sacc[ct] = c;
      }

      // ---- issue V^T frag loads NOW so they fly during softmax ----
      bf16x8 vf[8];
#pragma unroll
      for (int dt = 0; dt < 4; ++dt) {
        const unsigned short* vrow = Vt + base + (size_t)(dt * 16 + l16) * 2048 + jt * 64;
        vf[2 * dt]     = *(const bf16x8*)(vrow + quad * 8);
        vf[2 * dt + 1] = *(const bf16x8*)(vrow + 32 + quad * 8);
      }

      // ---- masked online softmax (C-layout: row=quad*4+reg, col=ct*16+l16) ----
      int padv[4];
#pragma unroll
      for (int ct = 0; ct < 4; ++ct) padv[ct] = pad[b * S_ + jt * 64 + ct * 16 + l16];

      const int grow0 = it * 64 + w * 16 + quad * 4;
      float alpha[4];
      float pv_[4][4];
#pragma unroll
      for (int reg = 0; reg < 4; ++reg) {
        const int gi = grow0 + reg;
        float lg[4];
        float mx = -INFINITY;
#pragma unroll
        for (int ct = 0; ct < 4; ++ct) {
          int gj = jt * 64 + ct * 16 + l16;
          bool ok = (gj <= gi) && (padv[ct] != 0);
          lg[ct] = ok ? sacc[ct][reg] * 0.125f : -INFINITY;
          mx = fmaxf(mx, lg[ct]);
        }
#pragma unroll
        for (int off = 1; off < 16; off <<= 1) mx = fmaxf(mx, __shfl_xor(mx, off, 64));
        float mnew = fmaxf(mrow[reg], mx);
        float a    = __expf(mrow[reg] - mnew);
        float sm   = 0.f;
#pragma unroll
        for (int ct = 0; ct < 4; ++ct) {
          float pe = __expf(lg[ct] - mnew);
          pv_[reg][ct] = pe;
          sm += pe;
        }
#pragma unroll
        for (int off = 1; off < 16; off <<= 1) sm += __shfl_xor(sm, off, 64);
        lrow[reg]  = lrow[reg] * a + sm;
        mrow[reg]  = mnew;
        alpha[reg] = a;
      }
#pragma unroll
      for (int dt = 0; dt < 4; ++dt)
#pragma unroll
        for (int reg = 0; reg < 4; ++reg) oacc[dt][reg] *= alpha[reg];

      // ---- P: C-layout -> A-layout via per-wave LDS strip (no barrier) ----
#pragma unroll
      for (int reg = 0; reg < 4; ++reg)
#pragma unroll
        for (int ct = 0; ct < 4; ++ct)
          Ps[w][quad * 4 + reg][ct * 16 + l16] = f2bf(pv_[reg][ct]);

      bf16x8 pfrag0 = *(const bf16x8*)&Ps[w][l16][quad * 8];
      bf16x8 pfrag1 = *(const bf16x8*)&Ps[w][l16][32 + quad * 8];

      // ---- PV (V^T frags already in registers) ----
#pragma unroll
      for (int dt = 0; dt < 4; ++dt) {
        oacc[dt] = __builtin_amdgcn_mfma_f32_16x16x32_bf16(pfrag0, vf[2 * dt],     oacc[dt], 0, 0, 0);
        oacc[dt] = __builtin_amdgcn_mfma_f32_16x16x32_bf16(pfrag1, vf[2 * dt + 1], oacc[dt], 0, 0, 0);
      }
    }

    // epilogue: normalize, write bf16 in place over Qb (own rows only)
#pragma unroll
    for (int reg = 0; reg < 4; ++reg) {
      const float rl = 1.0f / lrow[reg];
      unsigned short* orow = Qb + base + (size_t)(it * 64 + w * 16 + quad * 4 + reg) * 64;
#pragma unroll
      for (int dt = 0; dt < 4; ++dt)
        orow[dt * 16 + l16] = f2bf(oacc[dt][reg] * rl);
    }
  }
}

// ---------------------------------------------------------------------------
// Residual + LayerNorm; O is bf16.
// ---------------------------------------------------------------------------
__global__ __launch_bounds__(256) void ln_kernel(
    const float* __restrict__ x, const unsigned short* __restrict__ O,
    const float* __restrict__ gamma, const float* __restrict__ beta,
    float* __restrict__ out)
{
  __shared__ float red[8];
  const int row = blockIdx.x;
  const int tid = threadIdx.x;
  float4 xv = ((const float4*)x)[(size_t)row * 256 + tid];
  us4 ov4 = *(const us4*)(O + (size_t)row * 1024 + tid * 4);
  float4 y = make_float4(xv.x + bf2f(ov4[0]), xv.y + bf2f(ov4[1]),
                         xv.z + bf2f(ov4[2]), xv.w + bf2f(ov4[3]));
  float s1 = y.x + y.y + y.z + y.w;
  float s2 = y.x*y.x + y.y*y.y + y.z*y.z + y.w*y.w;
#pragma unroll
  for (int off = 32; off >= 1; off >>= 1) {
    s1 += __shfl_xor(s1, off, 64);
    s2 += __shfl_xor(s2, off, 64);
  }
  if ((tid & 63) == 0) { red[tid >> 6] = s1; red[4 + (tid >> 6)] = s2; }
  __syncthreads();
  s1 = red[0] + red[1] + red[2] + red[3];
  s2 = red[4] + red[5] + red[6] + red[7];
  const float mean = s1 * (1.0f / 1024.0f);
  const float var  = fmaxf(s2 * (1.0f / 1024.0f) - mean * mean, 0.f);
  const float rstd = 1.0f / (sqrtf(var) + 1e-8f);
  float4 gv = ((const float4*)gamma)[tid];
  float4 bv = ((const float4*)beta)[tid];
  float4 r;
  r.x = gv.x * (y.x - mean) * rstd + bv.x;
  r.y = gv.y * (y.y - mean) * rstd + bv.y;
  r.z = gv.z * (y.z - mean) * rstd + bv.z;
  r.w = gv.w * (y.w - mean) * rstd + bv.w;
  ((float4*)out)[(size_t)row * 256 + tid] = r;
}

// ---------------------------------------------------------------------------
extern "C" void kernel_launch(void* const* d_in, const int* in_sizes, int n_in,
                              void* d_out, int out_size, void* d_ws, size_t ws_size,
                              hipStream_t stream)
{
  const float* q  = (const float*)d_in[0];
  const float* k  = (const float*)d_in[1];
  const float* v  = (const float*)d_in[2];
  // d_in[3] = causal tril mask — applied analytically (j<=i)
  const int*   pad = (const int*)d_in[4];
  const float* Wq = (const float*)d_in[5];
  const float* bq = (const float*)d_in[6];
  const float* Wk = (const float*)d_in[7];
  const float* bk = (const float*)d_in[8];
  const float* Wv = (const float*)d_in[9];
  const float* bv = (const float*)d_in[10];
  const float* Wo = (const float*)d_in[11];
  const float* bo = (const float*)d_in[12];
  const float* gamma = (const float*)d_in[13];
  const float* beta  = (const float*)d_in[14];
  float* out = (float*)d_out;

  char* ws = (char*)d_ws;
  const size_t MB = 1024 * 1024;
  unsigned short* Ac   = (unsigned short*)(ws);             // 16 MB bf16 staging
  unsigned short* Qb   = (unsigned short*)(ws + 16 * MB);   // 16 MB
  unsigned short* Kb   = (unsigned short*)(ws + 32 * MB);   // 16 MB
  unsigned short* Vb   = (unsigned short*)(ws + 48 * MB);   // 16 MB (flat V)
  unsigned short* Vtb  = (unsigned short*)(ws + 64 * MB);   // 16 MB (V^T per bh)
  unsigned short* Wall = (unsigned short*)(ws + 80 * MB);   // 8 MB (4 weights bf16)
  unsigned short* Obuf = Ac;                                // alias: Ac dead after V-GEMM

  dim3 gg(8, 64), bb(256);
  cvt_w<<<dim3(1024, 4), 256, 0, stream>>>(Wq, Wk, Wv, Wo, Wall);

  cvt_a<<<8192, 256, 0, stream>>>(q, Ac);
  gemm_mfma<<<gg, bb, 0, stream>>>(Ac, Wall + 0 * MB, bq, Qb);
  cvt_a<<<8192, 256, 0, stream>>>(k, Ac);
  gemm_mfma<<<gg, bb, 0, stream>>>(Ac, Wall + 1 * MB, bk, Kb);
  cvt_a<<<8192, 256, 0, stream>>>(v, Ac);
  gemm_mfma<<<gg, bb, 0, stream>>>(Ac, Wall + 2 * MB, bv, Vb);
  vtrans<<<dim3(32, 64), 256, 0, stream>>>(Vb, Vtb);

  attn_mfma<<<dim3(16, 64), 256, 0, stream>>>(Qb, Kb, Vtb, pad);  // Qb <- attn out

  gemm_mfma<<<gg, bb, 0, stream>>>(Qb, Wall + 3 * MB, bo, Obuf);
  ln_kernel<<<dim3(B_ * S_), 256, 0, stream>>>(q, Obuf, gamma, beta, out);
}